// Round 2
// baseline (113281.079 us; speedup 1.0000x reference)
//
#include <hip/hip_runtime.h>

#define T_STEPS 4096
#define RSIZE   2048
#define N_IN    8
#define N_OUT   4
#define NWG     256
#define NT      256
#define ROWS_PER_WG 8          // RSIZE / NWG
#define COLS_PER_TH 8          // RSIZE / NT
#define LIN_STRIDE  (RSIZE + N_IN)   // 2056 — readout weight row stride

// d_ws layout:
//   states: [T_STEPS][RSIZE] float   @ 0                (33.55 MB)
//   flags : [T_STEPS][NWG]   int     @ T_STEPS*RSIZE*4  ( 4.19 MB)

__global__ __launch_bounds__(256) void init_kernel(float* __restrict__ states,
                                                   int* __restrict__ flags) {
    int idx = blockIdx.x * 256 + threadIdx.x;          // 0 .. T_STEPS*NWG-1
    if (idx < T_STEPS * NWG) flags[idx] = (idx < NWG) ? 1 : 0;  // step 0 "ready"
    if (idx < RSIZE) states[idx] = 0.0f;               // x_0 = 0
}

__global__ __launch_bounds__(NT, 1) void reservoir_kernel(
    const float* __restrict__ W,        // [R][R]
    const float* __restrict__ Win,      // [R][8]
    const float* __restrict__ Wfb,      // [R][4]
    const float* __restrict__ inputs,   // [T][8]
    const float* __restrict__ outputs,  // [T][4]
    const float* __restrict__ noise,    // [T][R]
    float* __restrict__ states,         // [T][R]
    int* __restrict__ flags)            // [T][NWG]
{
    const int g    = blockIdx.x;    // WG id == producer chunk id
    const int t    = threadIdx.x;   // 0..255; also consumer chunk id it waits on
    const int lane = t & 63;
    const int wave = t >> 6;
    const int rg   = g * ROWS_PER_WG;       // first row owned by this WG
    const int c0   = t * COLS_PER_TH;       // first col owned by this thread

    // ---- W block into registers: rows [rg,rg+8) x cols [c0,c0+8) ----
    float w[ROWS_PER_WG][COLS_PER_TH];
    #pragma unroll
    for (int i = 0; i < ROWS_PER_WG; ++i) {
        const float4* p = (const float4*)(W + (size_t)(rg + i) * RSIZE + c0);
        float4 a = p[0], b = p[1];
        w[i][0] = a.x; w[i][1] = a.y; w[i][2] = a.z; w[i][3] = a.w;
        w[i][4] = b.x; w[i][5] = b.y; w[i][6] = b.z; w[i][7] = b.w;
    }

    // ---- epilogue lanes (t<8) keep their input/feedback weight rows ----
    float win[N_IN]  = {0};
    float wfb[N_OUT] = {0};
    if (t < ROWS_PER_WG) {
        const int r = rg + t;
        #pragma unroll
        for (int j = 0; j < N_IN; ++j)  win[j] = Win[r * N_IN + j];
        #pragma unroll
        for (int k = 0; k < N_OUT; ++k) wfb[k] = Wfb[r * N_OUT + k];
    }

    __shared__ float red[2][4][ROWS_PER_WG];   // parity double-buffer

    for (int n = 1; n < T_STEPS; ++n) {
        // ---- prefetch step-local data that does NOT depend on x (hides poll) ----
        float u[N_IN] = {0}, y[N_OUT] = {0}, nz = 0.0f;
        if (t < ROWS_PER_WG) {
            #pragma unroll
            for (int j = 0; j < N_IN; ++j)  u[j] = inputs[n * N_IN + j];
            #pragma unroll
            for (int k = 0; k < N_OUT; ++k) y[k] = outputs[(n - 1) * N_OUT + k];
            nz = noise[(size_t)n * RSIZE + rg + t];
        }

        // ---- wait for producer of my x-chunk of step n-1 (device-scope acquire) ----
        int* fp = flags + (n - 1) * NWG + t;
        while (__hip_atomic_load(fp, __ATOMIC_ACQUIRE, __HIP_MEMORY_SCOPE_AGENT) == 0) {
            __builtin_amdgcn_s_sleep(1);
        }

        // ---- load my 8 columns of x_{n-1} (agent-scope: read from coherence point) ----
        const float* xp = states + (size_t)(n - 1) * RSIZE + c0;
        float x[COLS_PER_TH];
        #pragma unroll
        for (int j = 0; j < COLS_PER_TH; ++j)
            x[j] = __hip_atomic_load(xp + j, __ATOMIC_RELAXED, __HIP_MEMORY_SCOPE_AGENT);

        // ---- partial dot products: 8 rows x my 8 cols ----
        float acc[ROWS_PER_WG];
        #pragma unroll
        for (int i = 0; i < ROWS_PER_WG; ++i) {
            float s = 0.0f;
            #pragma unroll
            for (int j = 0; j < COLS_PER_TH; ++j) s = fmaf(w[i][j], x[j], s);
            acc[i] = s;
        }

        // ---- 64-lane butterfly reduction (all 8 row-sums) ----
        #pragma unroll
        for (int m = 1; m < 64; m <<= 1) {
            #pragma unroll
            for (int i = 0; i < ROWS_PER_WG; ++i)
                acc[i] += __shfl_xor(acc[i], m, 64);
        }

        const int p = n & 1;
        if (lane == 0) {
            #pragma unroll
            for (int i = 0; i < ROWS_PER_WG; ++i) red[p][wave][i] = acc[i];
        }
        __syncthreads();

        // ---- epilogue: finish reduction, add input/feedback terms, tanh, noise ----
        if (t < ROWS_PER_WG) {
            float s = red[p][0][t] + red[p][1][t] + red[p][2][t] + red[p][3][t];
            #pragma unroll
            for (int j = 0; j < N_IN; ++j)  s = fmaf(win[j], u[j], s);
            #pragma unroll
            for (int k = 0; k < N_OUT; ++k) s = fmaf(wfb[k], y[k], s);
            float xn = tanhf(s) + nz;
            // agent-scope store: lands at the coherence point (LLC), no reliance
            // on release-fence L2 writeback lowering
            __hip_atomic_store(states + (size_t)n * RSIZE + rg + t, xn,
                               __ATOMIC_RELAXED, __HIP_MEMORY_SCOPE_AGENT);
        }
        // release: orders the wave's prior stores before the flag becomes visible
        if (t == 0) {
            __hip_atomic_store(flags + n * NWG + g, 1,
                               __ATOMIC_RELEASE, __HIP_MEMORY_SCOPE_AGENT);
        }
    }
}

__global__ __launch_bounds__(256) void readout_kernel(
    const float* __restrict__ states,   // [T][R]
    const float* __restrict__ inputs,   // [T][8]
    const float* __restrict__ lin_w,    // [4][2056]
    const float* __restrict__ lin_b,    // [4]
    float* __restrict__ out)            // [T][4]
{
    const int ti   = blockIdx.x;        // time index
    const int tid  = threadIdx.x;
    const int lane = tid & 63;
    const int wave = tid >> 6;
    const int c0   = tid * 8;

    const float* xp = states + (size_t)ti * RSIZE + c0;
    float4 xa = ((const float4*)xp)[0];
    float4 xb = ((const float4*)xp)[1];
    float x[8] = {xa.x, xa.y, xa.z, xa.w, xb.x, xb.y, xb.z, xb.w};

    float acc[N_OUT];
    #pragma unroll
    for (int o = 0; o < N_OUT; ++o) {
        const float4* lp = (const float4*)(lin_w + (size_t)o * LIN_STRIDE + c0);
        float4 la = lp[0], lb = lp[1];
        float s = 0.0f;
        s = fmaf(la.x, x[0], s); s = fmaf(la.y, x[1], s);
        s = fmaf(la.z, x[2], s); s = fmaf(la.w, x[3], s);
        s = fmaf(lb.x, x[4], s); s = fmaf(lb.y, x[5], s);
        s = fmaf(lb.z, x[6], s); s = fmaf(lb.w, x[7], s);
        acc[o] = s;
    }

    #pragma unroll
    for (int m = 1; m < 64; m <<= 1) {
        #pragma unroll
        for (int o = 0; o < N_OUT; ++o) acc[o] += __shfl_xor(acc[o], m, 64);
    }

    __shared__ float red[4][N_OUT];
    if (lane == 0) {
        #pragma unroll
        for (int o = 0; o < N_OUT; ++o) red[wave][o] = acc[o];
    }
    __syncthreads();

    if (tid < N_OUT) {
        float s = red[0][tid] + red[1][tid] + red[2][tid] + red[3][tid] + lin_b[tid];
        if (ti > 0) {   // states_u row 0 is zero
            #pragma unroll
            for (int j = 0; j < N_IN; ++j)
                s = fmaf(lin_w[(size_t)tid * LIN_STRIDE + RSIZE + j],
                         inputs[ti * N_IN + j], s);
        }
        out[ti * N_OUT + tid] = s;
    }
}

extern "C" void kernel_launch(void* const* d_in, const int* in_sizes, int n_in,
                              void* d_out, int out_size, void* d_ws, size_t ws_size,
                              hipStream_t stream) {
    const float* inputs  = (const float*)d_in[0];
    const float* outputs = (const float*)d_in[1];
    const float* W       = (const float*)d_in[2];
    const float* Win     = (const float*)d_in[3];
    const float* Wfb     = (const float*)d_in[4];
    const float* lin_w   = (const float*)d_in[5];
    const float* lin_b   = (const float*)d_in[6];
    const float* noise   = (const float*)d_in[7];
    float* out = (float*)d_out;

    float* states = (float*)d_ws;
    int*   flags  = (int*)((char*)d_ws + (size_t)T_STEPS * RSIZE * sizeof(float));

    hipLaunchKernelGGL(init_kernel, dim3((T_STEPS * NWG) / 256), dim3(256), 0, stream,
                       states, flags);
    hipLaunchKernelGGL(reservoir_kernel, dim3(NWG), dim3(NT), 0, stream,
                       W, Win, Wfb, inputs, outputs, noise, states, flags);
    hipLaunchKernelGGL(readout_kernel, dim3(T_STEPS), dim3(256), 0, stream,
                       states, inputs, lin_w, lin_b, out);
}

// Round 3
// 15564.243 us; speedup vs baseline: 7.2783x; 7.2783x over previous
//
#include <hip/hip_runtime.h>

#define T_STEPS 4096
#define RSIZE   2048
#define N_IN    8
#define N_OUT   4
#define NWG     256
#define NT      256
#define ROWS_PER_WG 8          // RSIZE / NWG
#define COLS_PER_TH 8          // RSIZE / NT
#define LIN_STRIDE  (RSIZE + N_IN)   // 2056 — readout weight row stride
#define SENTINEL    0x7FC00000u      // qNaN bit pattern; recurrence never produces it

// d_ws layout:
//   states: [T_STEPS][RSIZE] float @ 0   (33.55 MB). Row 0 = zeros; rows 1.. = sentinel
//   until written. Data IS the flag: a non-sentinel dword is a published value.

__global__ __launch_bounds__(256) void init_kernel(float4* __restrict__ states4) {
    int idx = blockIdx.x * 256 + threadIdx.x;        // 0 .. T*R/4-1
    const float s = __uint_as_float(SENTINEL);
    float4 v = (idx < RSIZE / 4) ? make_float4(0.f, 0.f, 0.f, 0.f)
                                 : make_float4(s, s, s, s);
    states4[idx] = v;
}

__global__ __launch_bounds__(NT, 1) void reservoir_kernel(
    const float* __restrict__ W,        // [R][R]
    const float* __restrict__ Win,      // [R][8]
    const float* __restrict__ Wfb,      // [R][4]
    const float* __restrict__ inputs,   // [T][8]
    const float* __restrict__ outputs,  // [T][4]
    const float* __restrict__ noise,    // [T][R]
    float* __restrict__ states)         // [T][R]
{
    const int g    = blockIdx.x;    // WG id == producer chunk id (rows 8g..8g+8)
    const int t    = threadIdx.x;   // 0..255; consumer of cols 8t..8t+8
    const int lane = t & 63;
    const int wave = t >> 6;
    const int rg   = g * ROWS_PER_WG;
    const int c0   = t * COLS_PER_TH;

    // ---- W block into registers: rows [rg,rg+8) x cols [c0,c0+8) ----
    float w[ROWS_PER_WG][COLS_PER_TH];
    #pragma unroll
    for (int i = 0; i < ROWS_PER_WG; ++i) {
        const float4* p = (const float4*)(W + (size_t)(rg + i) * RSIZE + c0);
        float4 a = p[0], b = p[1];
        w[i][0] = a.x; w[i][1] = a.y; w[i][2] = a.z; w[i][3] = a.w;
        w[i][4] = b.x; w[i][5] = b.y; w[i][6] = b.z; w[i][7] = b.w;
    }

    // ---- epilogue lanes (t<8) keep their input/feedback weight rows ----
    float win[N_IN]  = {0};
    float wfb[N_OUT] = {0};
    if (t < ROWS_PER_WG) {
        const int r = rg + t;
        #pragma unroll
        for (int j = 0; j < N_IN; ++j)  win[j] = Win[r * N_IN + j];
        #pragma unroll
        for (int k = 0; k < N_OUT; ++k) wfb[k] = Wfb[r * N_OUT + k];
    }

    __shared__ float red[2][4][ROWS_PER_WG];   // parity double-buffer

    for (int n = 1; n < T_STEPS; ++n) {
        // ---- prefetch step-local data that does NOT depend on x ----
        float u[N_IN] = {0}, y[N_OUT] = {0}, nz = 0.0f;
        if (t < ROWS_PER_WG) {
            #pragma unroll
            for (int j = 0; j < N_IN; ++j)  u[j] = inputs[n * N_IN + j];
            #pragma unroll
            for (int k = 0; k < N_OUT; ++k) y[k] = outputs[(n - 1) * N_OUT + k];
            nz = noise[(size_t)n * RSIZE + rg + t];
        }

        // ---- spin on my 8 columns of x_{n-1}: data IS the flag ----
        // relaxed agent-scope loads: plain global_load sc1, NO buffer_inv
        const float* xp = states + (size_t)(n - 1) * RSIZE + c0;
        float x[COLS_PER_TH];
        for (;;) {
            bool ready = true;
            #pragma unroll
            for (int j = 0; j < COLS_PER_TH; ++j) {
                x[j] = __hip_atomic_load(xp + j, __ATOMIC_RELAXED,
                                         __HIP_MEMORY_SCOPE_AGENT);
                ready &= (__float_as_uint(x[j]) != SENTINEL);
            }
            if (ready) break;
            __builtin_amdgcn_s_sleep(1);
        }

        // ---- partial dot products: 8 rows x my 8 cols ----
        float acc[ROWS_PER_WG];
        #pragma unroll
        for (int i = 0; i < ROWS_PER_WG; ++i) {
            float s = 0.0f;
            #pragma unroll
            for (int j = 0; j < COLS_PER_TH; ++j) s = fmaf(w[i][j], x[j], s);
            acc[i] = s;
        }

        // ---- 64-lane butterfly reduction (all 8 row-sums) ----
        #pragma unroll
        for (int m = 1; m < 64; m <<= 1) {
            #pragma unroll
            for (int i = 0; i < ROWS_PER_WG; ++i)
                acc[i] += __shfl_xor(acc[i], m, 64);
        }

        const int p = n & 1;
        if (lane == 0) {
            #pragma unroll
            for (int i = 0; i < ROWS_PER_WG; ++i) red[p][wave][i] = acc[i];
        }
        __syncthreads();

        // ---- epilogue: finish reduction, input/feedback terms, tanh, noise ----
        if (t < ROWS_PER_WG) {
            float s = red[p][0][t] + red[p][1][t] + red[p][2][t] + red[p][3][t];
            #pragma unroll
            for (int j = 0; j < N_IN; ++j)  s = fmaf(win[j], u[j], s);
            #pragma unroll
            for (int k = 0; k < N_OUT; ++k) s = fmaf(wfb[k], y[k], s);
            float xn = tanhf(s) + nz;
            // publish: relaxed agent-scope store (global_store sc1, NO buffer_wbl2)
            __hip_atomic_store(states + (size_t)n * RSIZE + rg + t, xn,
                               __ATOMIC_RELAXED, __HIP_MEMORY_SCOPE_AGENT);
        }
    }
}

__global__ __launch_bounds__(256) void readout_kernel(
    const float* __restrict__ states,   // [T][R]
    const float* __restrict__ inputs,   // [T][8]
    const float* __restrict__ lin_w,    // [4][2056]
    const float* __restrict__ lin_b,    // [4]
    float* __restrict__ out)            // [T][4]
{
    const int ti   = blockIdx.x;        // time index
    const int tid  = threadIdx.x;
    const int lane = tid & 63;
    const int wave = tid >> 6;
    const int c0   = tid * 8;

    const float* xp = states + (size_t)ti * RSIZE + c0;
    float4 xa = ((const float4*)xp)[0];
    float4 xb = ((const float4*)xp)[1];
    float x[8] = {xa.x, xa.y, xa.z, xa.w, xb.x, xb.y, xb.z, xb.w};

    float acc[N_OUT];
    #pragma unroll
    for (int o = 0; o < N_OUT; ++o) {
        const float4* lp = (const float4*)(lin_w + (size_t)o * LIN_STRIDE + c0);
        float4 la = lp[0], lb = lp[1];
        float s = 0.0f;
        s = fmaf(la.x, x[0], s); s = fmaf(la.y, x[1], s);
        s = fmaf(la.z, x[2], s); s = fmaf(la.w, x[3], s);
        s = fmaf(lb.x, x[4], s); s = fmaf(lb.y, x[5], s);
        s = fmaf(lb.z, x[6], s); s = fmaf(lb.w, x[7], s);
        acc[o] = s;
    }

    #pragma unroll
    for (int m = 1; m < 64; m <<= 1) {
        #pragma unroll
        for (int o = 0; o < N_OUT; ++o) acc[o] += __shfl_xor(acc[o], m, 64);
    }

    __shared__ float red[4][N_OUT];
    if (lane == 0) {
        #pragma unroll
        for (int o = 0; o < N_OUT; ++o) red[wave][o] = acc[o];
    }
    __syncthreads();

    if (tid < N_OUT) {
        float s = red[0][tid] + red[1][tid] + red[2][tid] + red[3][tid] + lin_b[tid];
        if (ti > 0) {   // states_u row 0 is zero
            #pragma unroll
            for (int j = 0; j < N_IN; ++j)
                s = fmaf(lin_w[(size_t)tid * LIN_STRIDE + RSIZE + j],
                         inputs[ti * N_IN + j], s);
        }
        out[ti * N_OUT + tid] = s;
    }
}

extern "C" void kernel_launch(void* const* d_in, const int* in_sizes, int n_in,
                              void* d_out, int out_size, void* d_ws, size_t ws_size,
                              hipStream_t stream) {
    const float* inputs  = (const float*)d_in[0];
    const float* outputs = (const float*)d_in[1];
    const float* W       = (const float*)d_in[2];
    const float* Win     = (const float*)d_in[3];
    const float* Wfb     = (const float*)d_in[4];
    const float* lin_w   = (const float*)d_in[5];
    const float* lin_b   = (const float*)d_in[6];
    const float* noise   = (const float*)d_in[7];
    float* out = (float*)d_out;

    float* states = (float*)d_ws;

    hipLaunchKernelGGL(init_kernel, dim3((T_STEPS * RSIZE / 4) / 256), dim3(256), 0,
                       stream, (float4*)states);
    hipLaunchKernelGGL(reservoir_kernel, dim3(NWG), dim3(NT), 0, stream,
                       W, Win, Wfb, inputs, outputs, noise, states);
    hipLaunchKernelGGL(readout_kernel, dim3(T_STEPS), dim3(256), 0, stream,
                       states, inputs, lin_w, lin_b, out);
}

// Round 4
// 7594.434 us; speedup vs baseline: 14.9163x; 2.0494x over previous
//
#include <hip/hip_runtime.h>

#define T_STEPS 4096
#define RSIZE   2048
#define N_IN    8
#define N_OUT   4
#define NWG     256
#define NT      256                  // 4 waves per WG
#define LIN_STRIDE  (RSIZE + N_IN)   // 2056 — readout weight row stride
#define SENTINEL    0x7FC00000u      // qNaN bits; recurrence never produces it

typedef float v4 __attribute__((ext_vector_type(4)));

// d_ws: states [T][R] float. Row 0 zeros, rows 1.. sentinel. Data IS the flag.

__global__ __launch_bounds__(256) void init_kernel(v4* __restrict__ states4) {
    int idx = blockIdx.x * 256 + threadIdx.x;        // 0 .. T*R/4-1
    const float s = __uint_as_float(SENTINEL);
    v4 v = (idx < RSIZE / 4) ? (v4){0.f, 0.f, 0.f, 0.f} : (v4){s, s, s, s};
    states4[idx] = v;
}

__device__ __forceinline__ float dot4(v4 a, v4 b) {
    float s = a.x * b.x;
    s = fmaf(a.y, b.y, s);
    s = fmaf(a.z, b.z, s);
    s = fmaf(a.w, b.w, s);
    return s;
}

__global__ __launch_bounds__(NT, 1) void reservoir_kernel(
    const float* __restrict__ W,        // [R][R]
    const float* __restrict__ Win,      // [R][8]
    const float* __restrict__ Wfb,      // [R][4]
    const float* __restrict__ inputs,   // [T][8]
    const float* __restrict__ outputs,  // [T][4]
    const float* __restrict__ noise,    // [T][R]
    float* __restrict__ states)         // [T][R]
{
    const int g    = blockIdx.x;
    const int t    = threadIdx.x;
    const int lane = t & 63;
    const int wv   = t >> 6;            // wave in WG: 0..3
    const int wid  = g * 4 + wv;        // global wave: 0..1023
    const int r0   = wid * 2;           // this wave's 2 rows

    // ---- W into registers: 2 rows x 32 cols/lane, cols = j*512 + lane*8 + k ----
    v4 wreg[2][4][2];
    #pragma unroll
    for (int i = 0; i < 2; ++i)
        #pragma unroll
        for (int j = 0; j < 4; ++j) {
            const float* p = W + (size_t)(r0 + i) * RSIZE + j * 512 + lane * 8;
            wreg[i][j][0] = *(const v4*)p;
            wreg[i][j][1] = *(const v4*)(p + 4);
        }

    // ---- lanes 0,1 keep Win/Wfb for their row ----
    float win[N_IN] = {0}, wfb[N_OUT] = {0};
    if (lane < 2) {
        const int r = r0 + lane;
        #pragma unroll
        for (int j = 0; j < N_IN; ++j)  win[j] = Win[r * N_IN + j];
        #pragma unroll
        for (int k = 0; k < N_OUT; ++k) wfb[k] = Wfb[r * N_OUT + k];
    }

    // parity double-buffered x in LDS
    __shared__ v4 xsh[2][RSIZE / 4];    // 16 KB
    const int fillc = wv * 512 + lane * 8;     // col this lane polls/fills
    const int fi    = fillc >> 2;              // v4 index

    for (int n = 1; n < T_STEPS; ++n) {
        // ---- pre-poll: terms that don't depend on x_{n-1} ----
        float pre = 0.0f, nz = 0.0f;
        if (lane < 2) {
            const int r = r0 + lane;
            nz = noise[(size_t)n * RSIZE + r];
            #pragma unroll
            for (int j = 0; j < N_IN; ++j)  pre = fmaf(win[j], inputs[n * N_IN + j], pre);
            #pragma unroll
            for (int k = 0; k < N_OUT; ++k) pre = fmaf(wfb[k], outputs[(n - 1) * N_OUT + k], pre);
        }

        // ---- poll my 8 contiguous cols of x_{n-1} (2x volatile dwordx4) ----
        const volatile v4* src =
            (const volatile v4*)(states + (size_t)(n - 1) * RSIZE + fillc);
        v4 a, b;
        for (;;) {
            a = src[0];
            b = src[1];
            bool ok = (__float_as_uint(a.x) != SENTINEL) &
                      (__float_as_uint(a.y) != SENTINEL) &
                      (__float_as_uint(a.z) != SENTINEL) &
                      (__float_as_uint(a.w) != SENTINEL) &
                      (__float_as_uint(b.x) != SENTINEL) &
                      (__float_as_uint(b.y) != SENTINEL) &
                      (__float_as_uint(b.z) != SENTINEL) &
                      (__float_as_uint(b.w) != SENTINEL);
            if (ok) break;
            __builtin_amdgcn_s_sleep(1);
        }

        const int p = (n - 1) & 1;
        xsh[p][fi]     = a;
        xsh[p][fi + 1] = b;
        __syncthreads();

        // ---- 2-row dot over all 2048 cols from LDS ----
        float acc0 = 0.0f, acc1 = 0.0f;
        #pragma unroll
        for (int j = 0; j < 4; ++j) {
            const int xi = j * 128 + lane * 2;
            v4 x0 = xsh[p][xi];
            v4 x1 = xsh[p][xi + 1];
            acc0 += dot4(wreg[0][j][0], x0) + dot4(wreg[0][j][1], x1);
            acc1 += dot4(wreg[1][j][0], x0) + dot4(wreg[1][j][1], x1);
        }

        // ---- 64-lane butterfly: every lane ends with both row totals ----
        #pragma unroll
        for (int m = 1; m < 64; m <<= 1) {
            acc0 += __shfl_xor(acc0, m, 64);
            acc1 += __shfl_xor(acc1, m, 64);
        }

        // ---- epilogue + publish (lanes 0,1) ----
        if (lane < 2) {
            float s  = (lane == 0 ? acc0 : acc1) + pre;
            float xn = tanhf(s) + nz;
            *(volatile float*)(states + (size_t)n * RSIZE + r0 + lane) = xn;
        }
        __builtin_amdgcn_s_waitcnt(0);   // flush publish promptly
    }
}

__global__ __launch_bounds__(256) void readout_kernel(
    const float* __restrict__ states,   // [T][R]
    const float* __restrict__ inputs,   // [T][8]
    const float* __restrict__ lin_w,    // [4][2056]
    const float* __restrict__ lin_b,    // [4]
    float* __restrict__ out)            // [T][4]
{
    const int ti   = blockIdx.x;
    const int tid  = threadIdx.x;
    const int lane = tid & 63;
    const int wave = tid >> 6;
    const int c0   = tid * 8;

    const float* xp = states + (size_t)ti * RSIZE + c0;
    v4 xa = *(const v4*)xp;
    v4 xb = *(const v4*)(xp + 4);

    float acc[N_OUT];
    #pragma unroll
    for (int o = 0; o < N_OUT; ++o) {
        const float* lp = lin_w + (size_t)o * LIN_STRIDE + c0;
        v4 la = *(const v4*)lp;
        v4 lb = *(const v4*)(lp + 4);
        acc[o] = dot4(la, xa) + dot4(lb, xb);
    }

    #pragma unroll
    for (int m = 1; m < 64; m <<= 1) {
        #pragma unroll
        for (int o = 0; o < N_OUT; ++o) acc[o] += __shfl_xor(acc[o], m, 64);
    }

    __shared__ float red[4][N_OUT];
    if (lane == 0) {
        #pragma unroll
        for (int o = 0; o < N_OUT; ++o) red[wave][o] = acc[o];
    }
    __syncthreads();

    if (tid < N_OUT) {
        float s = red[0][tid] + red[1][tid] + red[2][tid] + red[3][tid] + lin_b[tid];
        if (ti > 0) {   // states_u row 0 is zero
            #pragma unroll
            for (int j = 0; j < N_IN; ++j)
                s = fmaf(lin_w[(size_t)tid * LIN_STRIDE + RSIZE + j],
                         inputs[ti * N_IN + j], s);
        }
        out[ti * N_OUT + tid] = s;
    }
}

extern "C" void kernel_launch(void* const* d_in, const int* in_sizes, int n_in,
                              void* d_out, int out_size, void* d_ws, size_t ws_size,
                              hipStream_t stream) {
    const float* inputs  = (const float*)d_in[0];
    const float* outputs = (const float*)d_in[1];
    const float* W       = (const float*)d_in[2];
    const float* Win     = (const float*)d_in[3];
    const float* Wfb     = (const float*)d_in[4];
    const float* lin_w   = (const float*)d_in[5];
    const float* lin_b   = (const float*)d_in[6];
    const float* noise   = (const float*)d_in[7];
    float* out = (float*)d_out;

    float* states = (float*)d_ws;

    hipLaunchKernelGGL(init_kernel, dim3((T_STEPS * RSIZE / 4) / 256), dim3(256), 0,
                       stream, (v4*)states);
    hipLaunchKernelGGL(reservoir_kernel, dim3(NWG), dim3(NT), 0, stream,
                       W, Win, Wfb, inputs, outputs, noise, states);
    hipLaunchKernelGGL(readout_kernel, dim3(T_STEPS), dim3(256), 0, stream,
                       states, inputs, lin_w, lin_b, out);
}